// Round 1
// baseline (985.056 us; speedup 1.0000x reference)
//
#include <hip/hip_runtime.h>
#include <math.h>

#define VV 5
#define CC 16
#define DD 32
#define HH 256
#define WW 320
#define HW (HH*WW)

// ---------------------------------------------------------------------------
// Kernel 1: projection setup (single thread).
// Computes, for each src view v=1..4:  proj = mk_proj(p_v) @ inv(mk_proj(p_0))
// and stores rot (3x3, row-major) + trans (3) as 12 floats per view into M.
// ---------------------------------------------------------------------------
__global__ void k_setup(const float* __restrict__ projs, float* __restrict__ M) {
    if (threadIdx.x != 0 || blockIdx.x != 0) return;

    // mk_proj(view v): new = E; new[:3,:4] = K[:3,:3] @ E[:3,:4]
    float ref[16];
    {
        const float* E = projs + 0 * 32;       // projs[0, v, 0] : extrinsics
        const float* K = projs + 0 * 32 + 16;  // projs[0, v, 1] : intrinsics
        for (int i = 0; i < 16; i++) ref[i] = E[i];
        for (int i = 0; i < 3; i++)
            for (int j = 0; j < 4; j++) {
                float s = 0.f;
                for (int k = 0; k < 3; k++) s += K[i*4+k] * E[k*4+j];
                ref[i*4+j] = s;
            }
    }

    // Gauss-Jordan inverse of ref (4x4) with partial pivoting
    float a[16], inv[16];
    for (int i = 0; i < 16; i++) { a[i] = ref[i]; inv[i] = ((i % 5) == 0) ? 1.f : 0.f; }
    for (int col = 0; col < 4; col++) {
        int piv = col; float best = fabsf(a[col*4+col]);
        for (int r = col+1; r < 4; r++) {
            float v = fabsf(a[r*4+col]);
            if (v > best) { best = v; piv = r; }
        }
        if (piv != col) {
            for (int j = 0; j < 4; j++) {
                float t = a[col*4+j]; a[col*4+j] = a[piv*4+j]; a[piv*4+j] = t;
                t = inv[col*4+j]; inv[col*4+j] = inv[piv*4+j]; inv[piv*4+j] = t;
            }
        }
        float rd = 1.f / a[col*4+col];
        for (int j = 0; j < 4; j++) { a[col*4+j] *= rd; inv[col*4+j] *= rd; }
        for (int r = 0; r < 4; r++) {
            if (r == col) continue;
            float f = a[r*4+col];
            for (int j = 0; j < 4; j++) {
                a[r*4+j]   -= f * a[col*4+j];
                inv[r*4+j] -= f * inv[col*4+j];
            }
        }
    }

    for (int v = 1; v < VV; v++) {
        float s[16], p[16];
        const float* E = projs + v * 32;
        const float* K = projs + v * 32 + 16;
        for (int i = 0; i < 16; i++) s[i] = E[i];
        for (int i = 0; i < 3; i++)
            for (int j = 0; j < 4; j++) {
                float acc = 0.f;
                for (int k = 0; k < 3; k++) acc += K[i*4+k] * E[k*4+j];
                s[i*4+j] = acc;
            }
        for (int i = 0; i < 4; i++)
            for (int j = 0; j < 4; j++) {
                float acc = 0.f;
                for (int k = 0; k < 4; k++) acc += s[i*4+k] * inv[k*4+j];
                p[i*4+j] = acc;
            }
        float* o = M + (v - 1) * 12;
        o[0] = p[0];  o[1] = p[1];  o[2]  = p[2];
        o[3] = p[4];  o[4] = p[5];  o[5]  = p[6];
        o[6] = p[8];  o[7] = p[9];  o[8]  = p[10];
        o[9] = p[3];  o[10] = p[7]; o[11] = p[11];
    }
}

// ---------------------------------------------------------------------------
// Kernel 2: variance cost volume. One thread per (d, y, x), loops C channels.
// var[c][d][y][x] = vol_sq/V - (vol_sum/V)^2
// ---------------------------------------------------------------------------
__global__ __launch_bounds__(WW) void k_var(const float* __restrict__ feat,
                                            const float* __restrict__ depth_vals,
                                            const float* __restrict__ M,
                                            float* __restrict__ var) {
    const int x = threadIdx.x;
    const int y = blockIdx.x;
    const int d = blockIdx.y;
    const int pix = y * WW + x;

    const float depth = depth_vals[d * HW + pix];

    float sum[CC], sq[CC];
    #pragma unroll
    for (int c = 0; c < CC; c++) {
        float r = feat[c * HW + pix];  // view 0 = reference
        sum[c] = r;
        sq[c]  = r * r;
    }

    const float fx = (float)x, fy = (float)y;
    for (int v = 1; v < VV; v++) {
        const float* m = M + (v - 1) * 12;
        float px = (m[0]*fx + m[1]*fy + m[2]) * depth + m[9];
        float py = (m[3]*fx + m[4]*fy + m[5]) * depth + m[10];
        float pz = (m[6]*fx + m[7]*fy + m[8]) * depth + m[11];
        px = px / pz;
        py = py / pz;

        float x0f = floorf(px), y0f = floorf(py);
        float wx = px - x0f,    wy = py - y0f;
        int x0 = (int)x0f, y0 = (int)y0f;
        int x1 = x0 + 1,   y1 = y0 + 1;

        float mx0 = (x0 >= 0 && x0 < WW) ? 1.f : 0.f;
        float mx1 = (x1 >= 0 && x1 < WW) ? 1.f : 0.f;
        float my0 = (y0 >= 0 && y0 < HH) ? 1.f : 0.f;
        float my1 = (y1 >= 0 && y1 < HH) ? 1.f : 0.f;

        int cx0 = min(max(x0, 0), WW - 1), cx1 = min(max(x1, 0), WW - 1);
        int cy0 = min(max(y0, 0), HH - 1), cy1 = min(max(y1, 0), HH - 1);

        float f00 = (1.f - wx) * (1.f - wy) * mx0 * my0;
        float f01 = wx * (1.f - wy)         * mx1 * my0;
        float f10 = (1.f - wx) * wy         * mx0 * my1;
        float f11 = wx * wy                 * mx1 * my1;

        int i00 = cy0 * WW + cx0, i01 = cy0 * WW + cx1;
        int i10 = cy1 * WW + cx0, i11 = cy1 * WW + cx1;

        const float* src = feat + (size_t)v * CC * HW;
        #pragma unroll
        for (int c = 0; c < CC; c++) {
            const float* s = src + c * HW;
            float wv = s[i00] * f00 + s[i01] * f01 + s[i10] * f10 + s[i11] * f11;
            sum[c] += wv;
            sq[c]  += wv * wv;
        }
    }

    const float invV = 1.f / (float)VV;
    #pragma unroll
    for (int c = 0; c < CC; c++) {
        float mean = sum[c] * invV;
        var[(size_t)c * DD * HW + (size_t)d * HW + pix] = sq[c] * invV - mean * mean;
    }
}

// ---------------------------------------------------------------------------
// Kernel 3: 3D convolution (C=16 in, 1 out, 3x3x3, SAME). Direct form.
// cost[d][y][x] = sum_{c,kd,ky,kx} w[c][kd][ky][kx] * var[c][d+kd-1][y+ky-1][x+kx-1]
// ---------------------------------------------------------------------------
__global__ __launch_bounds__(WW) void k_conv(const float* __restrict__ var,
                                             const float* __restrict__ w,
                                             float* __restrict__ cost) {
    __shared__ float sw[CC * 27];
    for (int i = threadIdx.x; i < CC * 27; i += blockDim.x) sw[i] = w[i];
    __syncthreads();

    const int x = threadIdx.x;
    const int y = blockIdx.x;
    const int d = blockIdx.y;

    float acc = 0.f;
    for (int c = 0; c < CC; c++) {
        const float* vc = var + (size_t)c * DD * HW;
        #pragma unroll
        for (int kd = 0; kd < 3; kd++) {
            int dd = d + kd - 1;
            if (dd < 0 || dd >= DD) continue;
            #pragma unroll
            for (int ky = 0; ky < 3; ky++) {
                int yy = y + ky - 1;
                if (yy < 0 || yy >= HH) continue;
                const float* row = vc + (size_t)dd * HW + yy * WW;
                #pragma unroll
                for (int kx = 0; kx < 3; kx++) {
                    int xx = x + kx - 1;
                    if (xx < 0 || xx >= WW) continue;
                    acc += sw[c*27 + kd*9 + ky*3 + kx] * row[xx];
                }
            }
        }
    }
    cost[(size_t)d * HW + y * WW + x] = acc;
}

// ---------------------------------------------------------------------------
// Kernel 4: softmax over D + depth regression + confidence.
// out layout: [0,HW) depth | [HW,2HW) conf | [2HW, 2HW+D*HW) prob
// ---------------------------------------------------------------------------
__global__ __launch_bounds__(256) void k_softmax(const float* __restrict__ cost,
                                                 const float* __restrict__ depth_vals,
                                                 float* __restrict__ out) {
    const int idx = blockIdx.x * blockDim.x + threadIdx.x;
    if (idx >= HW) return;

    float c[DD];
    float m = -INFINITY;
    #pragma unroll
    for (int d = 0; d < DD; d++) {
        c[d] = cost[(size_t)d * HW + idx];
        m = fmaxf(m, c[d]);
    }
    float s = 0.f;
    #pragma unroll
    for (int d = 0; d < DD; d++) {
        c[d] = expf(c[d] - m);
        s += c[d];
    }
    const float inv = 1.f / s;

    float depth = 0.f, di_f = 0.f;
    #pragma unroll
    for (int d = 0; d < DD; d++) {
        float p = c[d] * inv;
        c[d] = p;
        out[2 * HW + (size_t)d * HW + idx] = p;
        depth += p * depth_vals[(size_t)d * HW + idx];
        di_f  += p * (float)d;
    }
    out[idx] = depth;

    int di = (int)di_f;
    di = min(max(di, 0), DD - 1);
    float conf = c[di];
    if (di + 1 < DD) {
        // need c[di+1] with runtime index; recompute via unrolled select to
        // keep the array in registers
        float nxt = 0.f;
        #pragma unroll
        for (int d = 0; d < DD; d++) if (d == di + 1) nxt = c[d];
        conf += nxt;
    }
    // c[di] also needs a register-safe select:
    float cur = 0.f;
    #pragma unroll
    for (int d = 0; d < DD; d++) if (d == di) cur = c[d];
    conf = cur;
    {
        float nxt = 0.f;
        #pragma unroll
        for (int d = 0; d < DD; d++) if (d == di + 1) nxt = c[d];
        conf = cur + nxt;
    }
    out[HW + idx] = conf;
}

// ---------------------------------------------------------------------------
extern "C" void kernel_launch(void* const* d_in, const int* in_sizes, int n_in,
                              void* d_out, int out_size, void* d_ws, size_t ws_size,
                              hipStream_t stream) {
    const float* features = (const float*)d_in[0];
    const float* projs    = (const float*)d_in[1];
    const float* depthv   = (const float*)d_in[2];
    const float* regw     = (const float*)d_in[3];
    float* out = (float*)d_out;

    float* M    = (float*)d_ws;                    // 48 floats used, pad to 64
    float* var  = M + 64;                          // CC*DD*HW floats (168 MB)
    float* cost = var + (size_t)CC * DD * HW;      // DD*HW floats (10.5 MB)

    k_setup<<<1, 64, 0, stream>>>(projs, M);

    dim3 grid(HH, DD);
    k_var <<<grid, WW, 0, stream>>>(features, depthv, M, var);
    k_conv<<<grid, WW, 0, stream>>>(var, regw, cost);
    k_softmax<<<(HW + 255) / 256, 256, 0, stream>>>(cost, depthv, out);
}

// Round 2
// 412.897 us; speedup vs baseline: 2.3857x; 2.3857x over previous
//
#include <hip/hip_runtime.h>
#include <math.h>

#define VV 5
#define CC 16
#define DD 32
#define HH 256
#define WW 320
#define HW (HH*WW)
#define DSEG 8
#define NSEG (DD/DSEG)

// ---------------------------------------------------------------------------
// Kernel 1: projection setup (single thread). For each src view v=1..4:
// proj = mk_proj(p_v) @ inv(mk_proj(p_0)); store rot(3x3)+trans(3) in M.
// ---------------------------------------------------------------------------
__global__ void k_setup(const float* __restrict__ projs, float* __restrict__ M) {
    if (threadIdx.x != 0 || blockIdx.x != 0) return;

    float ref[16];
    {
        const float* E = projs + 0 * 32;
        const float* K = projs + 0 * 32 + 16;
        for (int i = 0; i < 16; i++) ref[i] = E[i];
        for (int i = 0; i < 3; i++)
            for (int j = 0; j < 4; j++) {
                float s = 0.f;
                for (int k = 0; k < 3; k++) s += K[i*4+k] * E[k*4+j];
                ref[i*4+j] = s;
            }
    }

    float a[16], inv[16];
    for (int i = 0; i < 16; i++) { a[i] = ref[i]; inv[i] = ((i % 5) == 0) ? 1.f : 0.f; }
    for (int col = 0; col < 4; col++) {
        int piv = col; float best = fabsf(a[col*4+col]);
        for (int r = col+1; r < 4; r++) {
            float v = fabsf(a[r*4+col]);
            if (v > best) { best = v; piv = r; }
        }
        if (piv != col) {
            for (int j = 0; j < 4; j++) {
                float t = a[col*4+j]; a[col*4+j] = a[piv*4+j]; a[piv*4+j] = t;
                t = inv[col*4+j]; inv[col*4+j] = inv[piv*4+j]; inv[piv*4+j] = t;
            }
        }
        float rd = 1.f / a[col*4+col];
        for (int j = 0; j < 4; j++) { a[col*4+j] *= rd; inv[col*4+j] *= rd; }
        for (int r = 0; r < 4; r++) {
            if (r == col) continue;
            float f = a[r*4+col];
            for (int j = 0; j < 4; j++) {
                a[r*4+j]   -= f * a[col*4+j];
                inv[r*4+j] -= f * inv[col*4+j];
            }
        }
    }

    for (int v = 1; v < VV; v++) {
        float s[16], p[16];
        const float* E = projs + v * 32;
        const float* K = projs + v * 32 + 16;
        for (int i = 0; i < 16; i++) s[i] = E[i];
        for (int i = 0; i < 3; i++)
            for (int j = 0; j < 4; j++) {
                float acc = 0.f;
                for (int k = 0; k < 3; k++) acc += K[i*4+k] * E[k*4+j];
                s[i*4+j] = acc;
            }
        for (int i = 0; i < 4; i++)
            for (int j = 0; j < 4; j++) {
                float acc = 0.f;
                for (int k = 0; k < 4; k++) acc += s[i*4+k] * inv[k*4+j];
                p[i*4+j] = acc;
            }
        float* o = M + (v - 1) * 12;
        o[0] = p[0];  o[1] = p[1];  o[2]  = p[2];
        o[3] = p[4];  o[4] = p[5];  o[5]  = p[6];
        o[6] = p[8];  o[7] = p[9];  o[8]  = p[10];
        o[9] = p[3];  o[10] = p[7]; o[11] = p[11];
    }
}

// ---------------------------------------------------------------------------
// Kernel 1b: transpose features [V][C][H][W] -> [V][H*W][C] (channel-last).
// ---------------------------------------------------------------------------
__global__ __launch_bounds__(256) void k_transpose(const float* __restrict__ feat,
                                                   float* __restrict__ tf) {
    const int idx = blockIdx.x * 256 + threadIdx.x;   // over V*HW
    if (idx >= VV * HW) return;
    const int v = idx / HW;
    const int pix = idx - v * HW;
    const float* src = feat + (size_t)v * CC * HW + pix;
    float t[CC];
    #pragma unroll
    for (int c = 0; c < CC; c++) t[c] = src[(size_t)c * HW];
    float4* dst = (float4*)(tf + (size_t)idx * CC);
    #pragma unroll
    for (int g = 0; g < 4; g++) {
        float4 o; o.x = t[4*g]; o.y = t[4*g+1]; o.z = t[4*g+2]; o.w = t[4*g+3];
        dst[g] = o;
    }
}

// ---------------------------------------------------------------------------
// Kernel 2 (fast path): variance volume from channel-last features.
// ---------------------------------------------------------------------------
__global__ __launch_bounds__(320) void k_var_t(const float* __restrict__ tf,
                                               const float* __restrict__ depth_vals,
                                               const float* __restrict__ M,
                                               float* __restrict__ var) {
    const int x = threadIdx.x;
    const int y = blockIdx.x;
    const int d = blockIdx.y;
    const int pix = y * WW + x;

    const float depth = depth_vals[(size_t)d * HW + pix];

    float sum[CC], sq[CC];
    {
        const float4* r0 = (const float4*)(tf + (size_t)pix * CC);
        #pragma unroll
        for (int g = 0; g < 4; g++) {
            float4 t = r0[g];
            sum[4*g+0] = t.x; sum[4*g+1] = t.y; sum[4*g+2] = t.z; sum[4*g+3] = t.w;
        }
        #pragma unroll
        for (int c = 0; c < CC; c++) sq[c] = sum[c] * sum[c];
    }

    const float fx = (float)x, fy = (float)y;
    for (int v = 1; v < VV; v++) {
        const float* m = M + (v - 1) * 12;
        float px = (m[0]*fx + m[1]*fy + m[2]) * depth + m[9];
        float py = (m[3]*fx + m[4]*fy + m[5]) * depth + m[10];
        float pz = (m[6]*fx + m[7]*fy + m[8]) * depth + m[11];
        px = px / pz;
        py = py / pz;

        float x0f = floorf(px), y0f = floorf(py);
        float wx = px - x0f,    wy = py - y0f;
        int x0 = (int)x0f, y0 = (int)y0f;
        int x1 = x0 + 1,   y1 = y0 + 1;

        float mx0 = (x0 >= 0 && x0 < WW) ? 1.f : 0.f;
        float mx1 = (x1 >= 0 && x1 < WW) ? 1.f : 0.f;
        float my0 = (y0 >= 0 && y0 < HH) ? 1.f : 0.f;
        float my1 = (y1 >= 0 && y1 < HH) ? 1.f : 0.f;

        int cx0 = min(max(x0, 0), WW - 1), cx1 = min(max(x1, 0), WW - 1);
        int cy0 = min(max(y0, 0), HH - 1), cy1 = min(max(y1, 0), HH - 1);

        float f00 = (1.f - wx) * (1.f - wy) * mx0 * my0;
        float f01 = wx * (1.f - wy)         * mx1 * my0;
        float f10 = (1.f - wx) * wy         * mx0 * my1;
        float f11 = wx * wy                 * mx1 * my1;

        int i00 = cy0 * WW + cx0, i01 = cy0 * WW + cx1;
        int i10 = cy1 * WW + cx0, i11 = cy1 * WW + cx1;

        const float* tfv = tf + (size_t)v * HW * CC;
        float wv[CC];
        #pragma unroll
        for (int c = 0; c < CC; c++) wv[c] = 0.f;

        #define GATHER_CORNER(IDX, F) { \
            const float4* p = (const float4*)(tfv + (size_t)(IDX) * CC); \
            float4 t0 = p[0], t1 = p[1], t2 = p[2], t3 = p[3]; \
            wv[0]  += (F)*t0.x; wv[1]  += (F)*t0.y; wv[2]  += (F)*t0.z; wv[3]  += (F)*t0.w; \
            wv[4]  += (F)*t1.x; wv[5]  += (F)*t1.y; wv[6]  += (F)*t1.z; wv[7]  += (F)*t1.w; \
            wv[8]  += (F)*t2.x; wv[9]  += (F)*t2.y; wv[10] += (F)*t2.z; wv[11] += (F)*t2.w; \
            wv[12] += (F)*t3.x; wv[13] += (F)*t3.y; wv[14] += (F)*t3.z; wv[15] += (F)*t3.w; }

        GATHER_CORNER(i00, f00)
        GATHER_CORNER(i01, f01)
        GATHER_CORNER(i10, f10)
        GATHER_CORNER(i11, f11)
        #undef GATHER_CORNER

        #pragma unroll
        for (int c = 0; c < CC; c++) {
            sum[c] += wv[c];
            sq[c]  += wv[c] * wv[c];
        }
    }

    const float invV = 1.f / (float)VV;
    #pragma unroll
    for (int c = 0; c < CC; c++) {
        float mean = sum[c] * invV;
        var[(size_t)c * DD * HW + (size_t)d * HW + pix] = sq[c] * invV - mean * mean;
    }
}

// ---------------------------------------------------------------------------
// Kernel 2 (fallback path): variance volume from original-layout features.
// ---------------------------------------------------------------------------
__global__ __launch_bounds__(320) void k_var_d(const float* __restrict__ feat,
                                               const float* __restrict__ depth_vals,
                                               const float* __restrict__ M,
                                               float* __restrict__ var) {
    const int x = threadIdx.x;
    const int y = blockIdx.x;
    const int d = blockIdx.y;
    const int pix = y * WW + x;

    const float depth = depth_vals[(size_t)d * HW + pix];

    float sum[CC], sq[CC];
    #pragma unroll
    for (int c = 0; c < CC; c++) {
        float r = feat[(size_t)c * HW + pix];
        sum[c] = r;
        sq[c]  = r * r;
    }

    const float fx = (float)x, fy = (float)y;
    for (int v = 1; v < VV; v++) {
        const float* m = M + (v - 1) * 12;
        float px = (m[0]*fx + m[1]*fy + m[2]) * depth + m[9];
        float py = (m[3]*fx + m[4]*fy + m[5]) * depth + m[10];
        float pz = (m[6]*fx + m[7]*fy + m[8]) * depth + m[11];
        px = px / pz;
        py = py / pz;

        float x0f = floorf(px), y0f = floorf(py);
        float wx = px - x0f,    wy = py - y0f;
        int x0 = (int)x0f, y0 = (int)y0f;
        int x1 = x0 + 1,   y1 = y0 + 1;

        float mx0 = (x0 >= 0 && x0 < WW) ? 1.f : 0.f;
        float mx1 = (x1 >= 0 && x1 < WW) ? 1.f : 0.f;
        float my0 = (y0 >= 0 && y0 < HH) ? 1.f : 0.f;
        float my1 = (y1 >= 0 && y1 < HH) ? 1.f : 0.f;

        int cx0 = min(max(x0, 0), WW - 1), cx1 = min(max(x1, 0), WW - 1);
        int cy0 = min(max(y0, 0), HH - 1), cy1 = min(max(y1, 0), HH - 1);

        float f00 = (1.f - wx) * (1.f - wy) * mx0 * my0;
        float f01 = wx * (1.f - wy)         * mx1 * my0;
        float f10 = (1.f - wx) * wy         * mx0 * my1;
        float f11 = wx * wy                 * mx1 * my1;

        int i00 = cy0 * WW + cx0, i01 = cy0 * WW + cx1;
        int i10 = cy1 * WW + cx0, i11 = cy1 * WW + cx1;

        const float* src = feat + (size_t)v * CC * HW;
        #pragma unroll
        for (int c = 0; c < CC; c++) {
            const float* s = src + (size_t)c * HW;
            float wv = s[i00] * f00 + s[i01] * f01 + s[i10] * f10 + s[i11] * f11;
            sum[c] += wv;
            sq[c]  += wv * wv;
        }
    }

    const float invV = 1.f / (float)VV;
    #pragma unroll
    for (int c = 0; c < CC; c++) {
        float mean = sum[c] * invV;
        var[(size_t)c * DD * HW + (size_t)d * HW + pix] = sq[c] * invV - mean * mean;
    }
}

// ---------------------------------------------------------------------------
// Kernel 3: 3D conv (16->1, 3x3x3, SAME), register-rolling over depth.
// Each thread: fixed (y,x), DSEG=8 depth outputs; dd window of DSEG+2 slices.
// var slice dd contributes to outputs dd-1, dd, dd+1 (o = s - kd, static).
// ---------------------------------------------------------------------------
__global__ __launch_bounds__(320) void k_conv(const float* __restrict__ var,
                                              const float* __restrict__ w,
                                              float* __restrict__ cost) {
    __shared__ float sw[CC * 27];
    for (int i = threadIdx.x; i < CC * 27; i += blockDim.x) sw[i] = w[i];
    __syncthreads();

    const int x  = threadIdx.x;
    const int y  = blockIdx.x;
    const int d0 = blockIdx.y * DSEG;

    float acc[DSEG];
    #pragma unroll
    for (int o = 0; o < DSEG; o++) acc[o] = 0.f;

    const bool y0ok = (y > 0), y2ok = (y < HH - 1);
    const bool xlok = (x > 0), xrok = (x < WW - 1);

    for (int c = 0; c < CC; c++) {
        float wr[27];
        #pragma unroll
        for (int i = 0; i < 27; i++) wr[i] = sw[c * 27 + i];

        const float* base = var + (size_t)c * DD * HW;

        #pragma unroll
        for (int s = 0; s < DSEG + 2; s++) {
            const int dd = d0 - 1 + s;
            if (dd < 0 || dd >= DD) continue;           // uniform branch

            float v00, v01, v02, v10, v11, v12, v20, v21, v22;
            const float* pr = base + (size_t)dd * HW + (size_t)y * WW + x;

            // ky = 1 (center row) always valid
            v11 = pr[0];
            v10 = xlok ? pr[-1] : 0.f;
            v12 = xrok ? pr[ 1] : 0.f;
            // ky = 0
            if (y0ok) {
                v01 = pr[-WW];
                v00 = xlok ? pr[-WW - 1] : 0.f;
                v02 = xrok ? pr[-WW + 1] : 0.f;
            } else { v00 = v01 = v02 = 0.f; }
            // ky = 2
            if (y2ok) {
                v21 = pr[WW];
                v20 = xlok ? pr[WW - 1] : 0.f;
                v22 = xrok ? pr[WW + 1] : 0.f;
            } else { v20 = v21 = v22 = 0.f; }

            #pragma unroll
            for (int kd = 0; kd < 3; kd++) {
                const int o = s - kd;
                if (o < 0 || o >= DSEG) continue;       // compile-time
                const float* k9 = wr + kd * 9;
                acc[o] += k9[0]*v00 + k9[1]*v01 + k9[2]*v02
                        + k9[3]*v10 + k9[4]*v11 + k9[5]*v12
                        + k9[6]*v20 + k9[7]*v21 + k9[8]*v22;
            }
        }
    }

    const int pix = y * WW + x;
    #pragma unroll
    for (int o = 0; o < DSEG; o++)
        cost[(size_t)(d0 + o) * HW + pix] = acc[o];
}

// ---------------------------------------------------------------------------
// Kernel 4: softmax over D + depth regression + confidence.
// out layout: [0,HW) depth | [HW,2HW) conf | [2HW, 2HW+D*HW) prob
// ---------------------------------------------------------------------------
__global__ __launch_bounds__(256) void k_softmax(const float* __restrict__ cost,
                                                 const float* __restrict__ depth_vals,
                                                 float* __restrict__ out) {
    const int idx = blockIdx.x * blockDim.x + threadIdx.x;
    if (idx >= HW) return;

    float c[DD];
    float m = -INFINITY;
    #pragma unroll
    for (int d = 0; d < DD; d++) {
        c[d] = cost[(size_t)d * HW + idx];
        m = fmaxf(m, c[d]);
    }
    float s = 0.f;
    #pragma unroll
    for (int d = 0; d < DD; d++) {
        c[d] = expf(c[d] - m);
        s += c[d];
    }
    const float inv = 1.f / s;

    float depth = 0.f, di_f = 0.f;
    #pragma unroll
    for (int d = 0; d < DD; d++) {
        float p = c[d] * inv;
        c[d] = p;
        out[2 * HW + (size_t)d * HW + idx] = p;
        depth += p * depth_vals[(size_t)d * HW + idx];
        di_f  += p * (float)d;
    }
    out[idx] = depth;

    int di = (int)di_f;
    di = min(max(di, 0), DD - 1);
    float cur = 0.f, nxt = 0.f;
    #pragma unroll
    for (int d = 0; d < DD; d++) {
        if (d == di)     cur = c[d];
        if (d == di + 1) nxt = c[d];
    }
    out[HW + idx] = cur + nxt;   // nxt stays 0 when di == DD-1
}

// ---------------------------------------------------------------------------
extern "C" void kernel_launch(void* const* d_in, const int* in_sizes, int n_in,
                              void* d_out, int out_size, void* d_ws, size_t ws_size,
                              hipStream_t stream) {
    const float* features = (const float*)d_in[0];
    const float* projs    = (const float*)d_in[1];
    const float* depthv   = (const float*)d_in[2];
    const float* regw     = (const float*)d_in[3];
    float* out = (float*)d_out;

    const size_t tf_elems   = (size_t)VV * HW * CC;      // 6.55M
    const size_t var_elems  = (size_t)CC * DD * HW;      // 41.9M
    const size_t cost_elems = (size_t)DD * HW;           // 2.62M
    const size_t need_tf = 4096 + (tf_elems + var_elems) * sizeof(float);
    const bool use_tf = (ws_size >= need_tf);

    float* M = (float*)d_ws;                             // 48 floats used

    k_setup<<<1, 64, 0, stream>>>(projs, M);

    dim3 grid(HH, DD);
    float* var;
    float* cost;
    if (use_tf) {
        float* tf = (float*)((char*)d_ws + 4096);
        var  = tf + tf_elems;
        cost = tf;                                       // tf dead after k_var
        k_transpose<<<(VV * HW + 255) / 256, 256, 0, stream>>>(features, tf);
        k_var_t<<<grid, WW, 0, stream>>>(tf, depthv, M, var);
    } else {
        var  = (float*)((char*)d_ws + 4096);
        cost = var + var_elems;
        (void)cost_elems;
        k_var_d<<<grid, WW, 0, stream>>>(features, depthv, M, var);
    }

    dim3 cgrid(HH, NSEG);
    k_conv<<<cgrid, WW, 0, stream>>>(var, regw, cost);
    k_softmax<<<(HW + 255) / 256, 256, 0, stream>>>(cost, depthv, out);
}

// Round 3
// 339.781 us; speedup vs baseline: 2.8991x; 1.2152x over previous
//
#include <hip/hip_runtime.h>
#include <math.h>

#define VV 5
#define CC 16
#define DD 32
#define HH 256
#define WW 320
#define HW (HH*WW)
#define ND 8            // depths per thread in k_var
#define DSEG 8          // depths per thread in k_conv
#define YSEG 2          // rows per thread in k_conv

// ---------------------------------------------------------------------------
// Kernel 1: projection setup (single thread). For each src view v=1..4:
// proj = mk_proj(p_v) @ inv(mk_proj(p_0)); store rot(3x3)+trans(3) in M.
// ---------------------------------------------------------------------------
__global__ void k_setup(const float* __restrict__ projs, float* __restrict__ M) {
    if (threadIdx.x != 0 || blockIdx.x != 0) return;

    float ref[16];
    {
        const float* E = projs + 0 * 32;
        const float* K = projs + 0 * 32 + 16;
        for (int i = 0; i < 16; i++) ref[i] = E[i];
        for (int i = 0; i < 3; i++)
            for (int j = 0; j < 4; j++) {
                float s = 0.f;
                for (int k = 0; k < 3; k++) s += K[i*4+k] * E[k*4+j];
                ref[i*4+j] = s;
            }
    }

    float a[16], inv[16];
    for (int i = 0; i < 16; i++) { a[i] = ref[i]; inv[i] = ((i % 5) == 0) ? 1.f : 0.f; }
    for (int col = 0; col < 4; col++) {
        int piv = col; float best = fabsf(a[col*4+col]);
        for (int r = col+1; r < 4; r++) {
            float v = fabsf(a[r*4+col]);
            if (v > best) { best = v; piv = r; }
        }
        if (piv != col) {
            for (int j = 0; j < 4; j++) {
                float t = a[col*4+j]; a[col*4+j] = a[piv*4+j]; a[piv*4+j] = t;
                t = inv[col*4+j]; inv[col*4+j] = inv[piv*4+j]; inv[piv*4+j] = t;
            }
        }
        float rd = 1.f / a[col*4+col];
        for (int j = 0; j < 4; j++) { a[col*4+j] *= rd; inv[col*4+j] *= rd; }
        for (int r = 0; r < 4; r++) {
            if (r == col) continue;
            float f = a[r*4+col];
            for (int j = 0; j < 4; j++) {
                a[r*4+j]   -= f * a[col*4+j];
                inv[r*4+j] -= f * inv[col*4+j];
            }
        }
    }

    for (int v = 1; v < VV; v++) {
        float s[16], p[16];
        const float* E = projs + v * 32;
        const float* K = projs + v * 32 + 16;
        for (int i = 0; i < 16; i++) s[i] = E[i];
        for (int i = 0; i < 3; i++)
            for (int j = 0; j < 4; j++) {
                float acc = 0.f;
                for (int k = 0; k < 3; k++) acc += K[i*4+k] * E[k*4+j];
                s[i*4+j] = acc;
            }
        for (int i = 0; i < 4; i++)
            for (int j = 0; j < 4; j++) {
                float acc = 0.f;
                for (int k = 0; k < 4; k++) acc += s[i*4+k] * inv[k*4+j];
                p[i*4+j] = acc;
            }
        float* o = M + (v - 1) * 12;
        o[0] = p[0];  o[1] = p[1];  o[2]  = p[2];
        o[3] = p[4];  o[4] = p[5];  o[5]  = p[6];
        o[6] = p[8];  o[7] = p[9];  o[8]  = p[10];
        o[9] = p[3];  o[10] = p[7]; o[11] = p[11];
    }
}

// ---------------------------------------------------------------------------
// Kernel 1b: transpose features [V][C][H][W] -> [V][H*W][C] (channel-last).
// ---------------------------------------------------------------------------
__global__ __launch_bounds__(256) void k_transpose(const float* __restrict__ feat,
                                                   float* __restrict__ tf) {
    const int idx = blockIdx.x * 256 + threadIdx.x;   // over V*HW
    if (idx >= VV * HW) return;
    const int v = idx / HW;
    const int pix = idx - v * HW;
    const float* src = feat + (size_t)v * CC * HW + pix;
    float t[CC];
    #pragma unroll
    for (int c = 0; c < CC; c++) t[c] = src[(size_t)c * HW];
    float4* dst = (float4*)(tf + (size_t)idx * CC);
    #pragma unroll
    for (int g = 0; g < 4; g++) {
        float4 o; o.x = t[4*g]; o.y = t[4*g+1]; o.z = t[4*g+2]; o.w = t[4*g+3];
        dst[g] = o;
    }
}

// ---------------------------------------------------------------------------
// Kernel 2: variance volume, channel-last features, ND depths per thread.
// Per-view row projection hoisted out of the depth loop; gathers for
// consecutive d trace an epipolar segment -> cache-local.
// ---------------------------------------------------------------------------
__global__ __launch_bounds__(320) void k_var_t(const float* __restrict__ tf,
                                               const float* __restrict__ depth_vals,
                                               const float* __restrict__ M,
                                               float* __restrict__ var) {
    const int x = threadIdx.x;
    const int y = blockIdx.x;
    const int dg = blockIdx.y;
    const int pix = y * WW + x;

    // reference features (view 0)
    float ref[CC];
    {
        const float4* r0 = (const float4*)(tf + (size_t)pix * CC);
        #pragma unroll
        for (int g = 0; g < 4; g++) {
            float4 t = r0[g];
            ref[4*g+0] = t.x; ref[4*g+1] = t.y; ref[4*g+2] = t.z; ref[4*g+3] = t.w;
        }
    }

    // hoist depth-independent projection rows per view
    const float fx = (float)x, fy = (float)y;
    float ax[4], ay[4], az[4], bx[4], by[4], bz[4];
    #pragma unroll
    for (int v = 0; v < 4; v++) {
        const float* m = M + v * 12;
        ax[v] = m[0]*fx + m[1]*fy + m[2];
        ay[v] = m[3]*fx + m[4]*fy + m[5];
        az[v] = m[6]*fx + m[7]*fy + m[8];
        bx[v] = m[9]; by[v] = m[10]; bz[v] = m[11];
    }

    #pragma unroll
    for (int dl = 0; dl < ND; dl++) {
        const int d = dg * ND + dl;
        const float depth = depth_vals[(size_t)d * HW + pix];

        float sum[CC], sq[CC];
        #pragma unroll
        for (int c = 0; c < CC; c++) { sum[c] = ref[c]; sq[c] = ref[c] * ref[c]; }

        #pragma unroll
        for (int v = 0; v < 4; v++) {
            float px = ax[v] * depth + bx[v];
            float py = ay[v] * depth + by[v];
            float pz = az[v] * depth + bz[v];
            px = px / pz;
            py = py / pz;

            float x0f = floorf(px), y0f = floorf(py);
            float wx = px - x0f,    wy = py - y0f;
            int x0 = (int)x0f, y0 = (int)y0f;
            int x1 = x0 + 1,   y1 = y0 + 1;

            float mx0 = (x0 >= 0 && x0 < WW) ? 1.f : 0.f;
            float mx1 = (x1 >= 0 && x1 < WW) ? 1.f : 0.f;
            float my0 = (y0 >= 0 && y0 < HH) ? 1.f : 0.f;
            float my1 = (y1 >= 0 && y1 < HH) ? 1.f : 0.f;

            int cx0 = min(max(x0, 0), WW - 1), cx1 = min(max(x1, 0), WW - 1);
            int cy0 = min(max(y0, 0), HH - 1), cy1 = min(max(y1, 0), HH - 1);

            float f00 = (1.f - wx) * (1.f - wy) * mx0 * my0;
            float f01 = wx * (1.f - wy)         * mx1 * my0;
            float f10 = (1.f - wx) * wy         * mx0 * my1;
            float f11 = wx * wy                 * mx1 * my1;

            int i00 = cy0 * WW + cx0, i01 = cy0 * WW + cx1;
            int i10 = cy1 * WW + cx0, i11 = cy1 * WW + cx1;

            const float* tfv = tf + (size_t)(v + 1) * HW * CC;
            float wv[CC];
            #pragma unroll
            for (int c = 0; c < CC; c++) wv[c] = 0.f;

            #define GATHER_CORNER(IDX, F) { \
                const float4* p = (const float4*)(tfv + (size_t)(IDX) * CC); \
                float4 t0 = p[0], t1 = p[1], t2 = p[2], t3 = p[3]; \
                wv[0]  += (F)*t0.x; wv[1]  += (F)*t0.y; wv[2]  += (F)*t0.z; wv[3]  += (F)*t0.w; \
                wv[4]  += (F)*t1.x; wv[5]  += (F)*t1.y; wv[6]  += (F)*t1.z; wv[7]  += (F)*t1.w; \
                wv[8]  += (F)*t2.x; wv[9]  += (F)*t2.y; wv[10] += (F)*t2.z; wv[11] += (F)*t2.w; \
                wv[12] += (F)*t3.x; wv[13] += (F)*t3.y; wv[14] += (F)*t3.z; wv[15] += (F)*t3.w; }

            GATHER_CORNER(i00, f00)
            GATHER_CORNER(i01, f01)
            GATHER_CORNER(i10, f10)
            GATHER_CORNER(i11, f11)
            #undef GATHER_CORNER

            #pragma unroll
            for (int c = 0; c < CC; c++) {
                sum[c] += wv[c];
                sq[c]  += wv[c] * wv[c];
            }
        }

        const float invV = 1.f / (float)VV;
        #pragma unroll
        for (int c = 0; c < CC; c++) {
            float mean = sum[c] * invV;
            var[(size_t)c * DD * HW + (size_t)d * HW + pix] = sq[c] * invV - mean * mean;
        }
    }
}

// ---------------------------------------------------------------------------
// Kernel 3: 3D conv (16->1, 3x3x3, SAME). Each thread: YSEG rows x DSEG
// depths at fixed x. Rolling window over depth; 4-row x 3-col patch per
// (c, slice) shared by all 16 outputs. Weights via uniform (SGPR) loads.
// ---------------------------------------------------------------------------
__global__ __launch_bounds__(320) void k_conv(const float* __restrict__ var,
                                              const float* __restrict__ w,
                                              float* __restrict__ cost) {
    const int x  = threadIdx.x;
    const int y0 = blockIdx.x * YSEG;
    const int d0 = blockIdx.y * DSEG;

    float acc[YSEG][DSEG];
    #pragma unroll
    for (int dy = 0; dy < YSEG; dy++)
        #pragma unroll
        for (int o = 0; o < DSEG; o++) acc[dy][o] = 0.f;

    const bool xlok = (x > 0), xrok = (x < WW - 1);

    for (int c = 0; c < CC; c++) {
        float wr[27];
        #pragma unroll
        for (int i = 0; i < 27; i++) wr[i] = w[c * 27 + i];   // uniform -> SGPR

        const float* base = var + (size_t)c * DD * HW;

        #pragma unroll
        for (int s = 0; s < DSEG + 2; s++) {
            const int dd = d0 - 1 + s;
            if (dd < 0 || dd >= DD) continue;               // uniform branch

            float v[YSEG + 2][3];
            #pragma unroll
            for (int r = 0; r < YSEG + 2; r++) {
                const int yy = y0 - 1 + r;
                if (yy < 0 || yy >= HH) {                    // uniform per block
                    v[r][0] = v[r][1] = v[r][2] = 0.f;
                } else {
                    const float* pr = base + (size_t)dd * HW + (size_t)yy * WW + x;
                    v[r][1] = pr[0];
                    v[r][0] = xlok ? pr[-1] : 0.f;
                    v[r][2] = xrok ? pr[ 1] : 0.f;
                }
            }

            #pragma unroll
            for (int dy = 0; dy < YSEG; dy++) {
                #pragma unroll
                for (int kd = 0; kd < 3; kd++) {
                    const int o = s - kd;
                    if (o < 0 || o >= DSEG) continue;        // compile-time
                    const float* k9 = wr + kd * 9;
                    acc[dy][o] += k9[0]*v[dy+0][0] + k9[1]*v[dy+0][1] + k9[2]*v[dy+0][2]
                                + k9[3]*v[dy+1][0] + k9[4]*v[dy+1][1] + k9[5]*v[dy+1][2]
                                + k9[6]*v[dy+2][0] + k9[7]*v[dy+2][1] + k9[8]*v[dy+2][2];
                }
            }
        }
    }

    #pragma unroll
    for (int dy = 0; dy < YSEG; dy++) {
        const int pix = (y0 + dy) * WW + x;
        #pragma unroll
        for (int o = 0; o < DSEG; o++)
            cost[(size_t)(d0 + o) * HW + pix] = acc[dy][o];
    }
}

// ---------------------------------------------------------------------------
// Kernel 4: softmax over D + depth regression + confidence.
// out layout: [0,HW) depth | [HW,2HW) conf | [2HW, 2HW+D*HW) prob
// ---------------------------------------------------------------------------
__global__ __launch_bounds__(256) void k_softmax(const float* __restrict__ cost,
                                                 const float* __restrict__ depth_vals,
                                                 float* __restrict__ out) {
    const int idx = blockIdx.x * blockDim.x + threadIdx.x;
    if (idx >= HW) return;

    float c[DD];
    float m = -INFINITY;
    #pragma unroll
    for (int d = 0; d < DD; d++) {
        c[d] = cost[(size_t)d * HW + idx];
        m = fmaxf(m, c[d]);
    }
    float s = 0.f;
    #pragma unroll
    for (int d = 0; d < DD; d++) {
        c[d] = expf(c[d] - m);
        s += c[d];
    }
    const float inv = 1.f / s;

    float depth = 0.f, di_f = 0.f;
    #pragma unroll
    for (int d = 0; d < DD; d++) {
        float p = c[d] * inv;
        c[d] = p;
        out[2 * HW + (size_t)d * HW + idx] = p;
        depth += p * depth_vals[(size_t)d * HW + idx];
        di_f  += p * (float)d;
    }
    out[idx] = depth;

    int di = (int)di_f;
    di = min(max(di, 0), DD - 1);
    float cur = 0.f, nxt = 0.f;
    #pragma unroll
    for (int d = 0; d < DD; d++) {
        if (d == di)     cur = c[d];
        if (d == di + 1) nxt = c[d];
    }
    out[HW + idx] = cur + nxt;   // nxt stays 0 when di == DD-1
}

// ---------------------------------------------------------------------------
extern "C" void kernel_launch(void* const* d_in, const int* in_sizes, int n_in,
                              void* d_out, int out_size, void* d_ws, size_t ws_size,
                              hipStream_t stream) {
    const float* features = (const float*)d_in[0];
    const float* projs    = (const float*)d_in[1];
    const float* depthv   = (const float*)d_in[2];
    const float* regw     = (const float*)d_in[3];
    float* out = (float*)d_out;

    const size_t tf_elems  = (size_t)VV * HW * CC;       // 6.55M
    const size_t var_elems = (size_t)CC * DD * HW;       // 41.9M

    float* M = (float*)d_ws;                             // 48 floats used
    float* tf   = (float*)((char*)d_ws + 4096);
    float* var  = tf + tf_elems;
    float* cost = tf;                                    // tf dead after k_var

    k_setup<<<1, 64, 0, stream>>>(projs, M);
    k_transpose<<<(VV * HW + 255) / 256, 256, 0, stream>>>(features, tf);

    dim3 vgrid(HH, DD / ND);
    k_var_t<<<vgrid, WW, 0, stream>>>(tf, depthv, M, var);

    dim3 cgrid(HH / YSEG, DD / DSEG);
    k_conv<<<cgrid, WW, 0, stream>>>(var, regw, cost);

    k_softmax<<<(HW + 255) / 256, 256, 0, stream>>>(cost, depthv, out);
}